// Round 1
// baseline (1046.436 us; speedup 1.0000x reference)
//
#include <hip/hip_runtime.h>
#include <math.h>

#define B_SIZE 8192
#define D_SIZE 256
#define ALPHA 2.0f
#define BETA 50.0f
#define BASE 0.5f
#define MARGIN 0.1f

#define BM 64
#define BN 64
#define BK 16
#define PAD 4

// Order-preserving float <-> uint32 map (for atomic min/max on floats)
__device__ __forceinline__ unsigned int enc_f32(float f) {
    unsigned int u = __float_as_uint(f);
    return (u & 0x80000000u) ? ~u : (u | 0x80000000u);
}
__device__ __forceinline__ float dec_f32(unsigned int e) {
    unsigned int u = (e & 0x80000000u) ? (e ^ 0x80000000u) : ~e;
    return __uint_as_float(u);
}

__global__ void init_kernel(unsigned int* __restrict__ pme, unsigned int* __restrict__ nme,
                            float* __restrict__ sp, float* __restrict__ sn) {
    int i = blockIdx.x * 256 + threadIdx.x;
    if (i < B_SIZE) {
        pme[i] = 0xFF800000u;   // enc(+inf)
        nme[i] = 0x007FFFFFu;   // enc(-inf)
        sp[i] = 0.0f;
        sn[i] = 0.0f;
    }
}

// ---- Pass 1: per-row pos_min / neg_max over the sim matrix ----
__global__ __launch_bounds__(256) void pass1_kernel(
    const float* __restrict__ emb, const int* __restrict__ labels,
    unsigned int* __restrict__ pos_min_enc, unsigned int* __restrict__ neg_max_enc)
{
    __shared__ float As[BK][BM + PAD];
    __shared__ float Bs[BK][BN + PAD];
    const int tid = threadIdx.x;
    const int m0 = blockIdx.y * BM;
    const int n0 = blockIdx.x * BN;
    const int tx = tid & 15;
    const int ty = tid >> 4;
    const int lr = tid >> 2;        // loader row 0..63
    const int lk = (tid & 3) * 4;   // loader k offset 0,4,8,12

    float acc[4][4] = {};
    for (int k0 = 0; k0 < D_SIZE; k0 += BK) {
        float4 av = *(const float4*)(&emb[(size_t)(m0 + lr) * D_SIZE + k0 + lk]);
        float4 bv = *(const float4*)(&emb[(size_t)(n0 + lr) * D_SIZE + k0 + lk]);
        __syncthreads();
        As[lk + 0][lr] = av.x; As[lk + 1][lr] = av.y; As[lk + 2][lr] = av.z; As[lk + 3][lr] = av.w;
        Bs[lk + 0][lr] = bv.x; Bs[lk + 1][lr] = bv.y; Bs[lk + 2][lr] = bv.z; Bs[lk + 3][lr] = bv.w;
        __syncthreads();
#pragma unroll
        for (int k = 0; k < BK; ++k) {
            float4 a4 = *(const float4*)(&As[k][ty * 4]);
            float4 b4 = *(const float4*)(&Bs[k][tx * 4]);
            float ar[4] = {a4.x, a4.y, a4.z, a4.w};
            float br[4] = {b4.x, b4.y, b4.z, b4.w};
#pragma unroll
            for (int i = 0; i < 4; ++i)
#pragma unroll
                for (int j = 0; j < 4; ++j)
                    acc[i][j] = fmaf(ar[i], br[j], acc[i][j]);
        }
    }

    // Epilogue: per-row min over positives, max over negatives
    int gi[4], li[4], gj[4], lj[4];
#pragma unroll
    for (int i = 0; i < 4; ++i) { gi[i] = m0 + ty * 4 + i; li[i] = labels[gi[i]]; }
#pragma unroll
    for (int j = 0; j < 4; ++j) { gj[j] = n0 + tx * 4 + j; lj[j] = labels[gj[j]]; }

    float minp[4], maxn[4];
#pragma unroll
    for (int i = 0; i < 4; ++i) { minp[i] = __builtin_inff(); maxn[i] = -__builtin_inff(); }

#pragma unroll
    for (int i = 0; i < 4; ++i) {
#pragma unroll
        for (int j = 0; j < 4; ++j) {
            if (gi[i] == gj[j]) continue;
            float s = acc[i][j];
            if (li[i] == lj[j]) minp[i] = fminf(minp[i], s);
            else                maxn[i] = fmaxf(maxn[i], s);
        }
    }
    // reduce across the 16 lanes sharing the same rows (tid = ty*16+tx, groups contiguous in-wave)
#pragma unroll
    for (int m = 1; m < 16; m <<= 1) {
#pragma unroll
        for (int i = 0; i < 4; ++i) {
            minp[i] = fminf(minp[i], __shfl_xor(minp[i], m, 64));
            maxn[i] = fmaxf(maxn[i], __shfl_xor(maxn[i], m, 64));
        }
    }
    if (tx == 0) {
#pragma unroll
        for (int i = 0; i < 4; ++i) {
            if (minp[i] < __builtin_inff())  atomicMin(&pos_min_enc[gi[i]], enc_f32(minp[i]));
            if (maxn[i] > -__builtin_inff()) atomicMax(&neg_max_enc[gi[i]], enc_f32(maxn[i]));
        }
    }
}

// ---- Pass 2: recompute sim, accumulate masked exp-sums per row ----
__global__ __launch_bounds__(256) void pass2_kernel(
    const float* __restrict__ emb, const int* __restrict__ labels,
    const unsigned int* __restrict__ pos_min_enc, const unsigned int* __restrict__ neg_max_enc,
    float* __restrict__ sum_pos, float* __restrict__ sum_neg)
{
    __shared__ float As[BK][BM + PAD];
    __shared__ float Bs[BK][BN + PAD];
    const int tid = threadIdx.x;
    const int m0 = blockIdx.y * BM;
    const int n0 = blockIdx.x * BN;
    const int tx = tid & 15;
    const int ty = tid >> 4;
    const int lr = tid >> 2;
    const int lk = (tid & 3) * 4;

    float acc[4][4] = {};
    for (int k0 = 0; k0 < D_SIZE; k0 += BK) {
        float4 av = *(const float4*)(&emb[(size_t)(m0 + lr) * D_SIZE + k0 + lk]);
        float4 bv = *(const float4*)(&emb[(size_t)(n0 + lr) * D_SIZE + k0 + lk]);
        __syncthreads();
        As[lk + 0][lr] = av.x; As[lk + 1][lr] = av.y; As[lk + 2][lr] = av.z; As[lk + 3][lr] = av.w;
        Bs[lk + 0][lr] = bv.x; Bs[lk + 1][lr] = bv.y; Bs[lk + 2][lr] = bv.z; Bs[lk + 3][lr] = bv.w;
        __syncthreads();
#pragma unroll
        for (int k = 0; k < BK; ++k) {
            float4 a4 = *(const float4*)(&As[k][ty * 4]);
            float4 b4 = *(const float4*)(&Bs[k][tx * 4]);
            float ar[4] = {a4.x, a4.y, a4.z, a4.w};
            float br[4] = {b4.x, b4.y, b4.z, b4.w};
#pragma unroll
            for (int i = 0; i < 4; ++i)
#pragma unroll
                for (int j = 0; j < 4; ++j)
                    acc[i][j] = fmaf(ar[i], br[j], acc[i][j]);
        }
    }

    int gi[4], li[4], gj[4], lj[4];
#pragma unroll
    for (int i = 0; i < 4; ++i) { gi[i] = m0 + ty * 4 + i; li[i] = labels[gi[i]]; }
#pragma unroll
    for (int j = 0; j < 4; ++j) { gj[j] = n0 + tx * 4 + j; lj[j] = labels[gj[j]]; }

    float pm[4], nm[4], sp[4], sn[4];
#pragma unroll
    for (int i = 0; i < 4; ++i) {
        pm[i] = dec_f32(pos_min_enc[gi[i]]);
        nm[i] = dec_f32(neg_max_enc[gi[i]]);
        sp[i] = 0.0f; sn[i] = 0.0f;
    }

#pragma unroll
    for (int i = 0; i < 4; ++i) {
#pragma unroll
        for (int j = 0; j < 4; ++j) {
            if (gi[i] == gj[j]) continue;
            float s = acc[i][j];
            if (li[i] == lj[j]) {
                if (s - MARGIN < nm[i]) sp[i] += expf(-ALPHA * (s - BASE));
            } else {
                if (s + MARGIN > pm[i]) sn[i] += expf(BETA * (s - BASE));
            }
        }
    }
#pragma unroll
    for (int m = 1; m < 16; m <<= 1) {
#pragma unroll
        for (int i = 0; i < 4; ++i) {
            sp[i] += __shfl_xor(sp[i], m, 64);
            sn[i] += __shfl_xor(sn[i], m, 64);
        }
    }
    if (tx == 0) {
#pragma unroll
        for (int i = 0; i < 4; ++i) {
            if (sp[i] > 0.0f) atomicAdd(&sum_pos[gi[i]], sp[i]);
            if (sn[i] > 0.0f) atomicAdd(&sum_neg[gi[i]], sn[i]);
        }
    }
}

// ---- Finalize: per-row terms, masked mean ----
__global__ void finalize_kernel(const float* __restrict__ sum_pos, const float* __restrict__ sum_neg,
                                float* __restrict__ out)
{
    __shared__ float st[256];
    __shared__ float sc[256];
    const int tid = threadIdx.x;
    float tot = 0.0f, cnt = 0.0f;
    for (int i = tid; i < B_SIZE; i += 256) {
        float sp = sum_pos[i], sn = sum_neg[i];
        if (sp > 0.0f && sn > 0.0f) {
            tot += log1pf(sp) * (1.0f / ALPHA) + log1pf(sn) * (1.0f / BETA);
            cnt += 1.0f;
        }
    }
    st[tid] = tot; sc[tid] = cnt;
    __syncthreads();
    for (int s = 128; s > 0; s >>= 1) {
        if (tid < s) { st[tid] += st[tid + s]; sc[tid] += sc[tid + s]; }
        __syncthreads();
    }
    if (tid == 0) out[0] = st[0] / fmaxf(sc[0], 1.0f);
}

extern "C" void kernel_launch(void* const* d_in, const int* in_sizes, int n_in,
                              void* d_out, int out_size, void* d_ws, size_t ws_size,
                              hipStream_t stream) {
    const float* emb = (const float*)d_in[0];
    const int* labels = (const int*)d_in[1];
    float* out = (float*)d_out;

    unsigned int* pme = (unsigned int*)d_ws;
    unsigned int* nme = pme + B_SIZE;
    float* sum_pos = (float*)(nme + B_SIZE);
    float* sum_neg = sum_pos + B_SIZE;

    init_kernel<<<dim3(B_SIZE / 256), dim3(256), 0, stream>>>(pme, nme, sum_pos, sum_neg);

    dim3 grid(B_SIZE / BN, B_SIZE / BM);
    dim3 block(256);
    pass1_kernel<<<grid, block, 0, stream>>>(emb, labels, pme, nme);
    pass2_kernel<<<grid, block, 0, stream>>>(emb, labels, pme, nme, sum_pos, sum_neg);
    finalize_kernel<<<1, dim3(256), 0, stream>>>(sum_pos, sum_neg, out);
}

// Round 2
// 340.235 us; speedup vs baseline: 3.0756x; 3.0756x over previous
//
#include <hip/hip_runtime.h>
#include <math.h>

#define B_SIZE 8192
#define D_SIZE 256
#define ALPHA 2.0f
#define BETA 50.0f
#define BASE 0.5f
#define MARGIN 0.1f

// MFMA GEMM tiling: 128x128 block tile, BK=32, 256 threads = 4 waves (2x2 of 64x64)
#define TM 128
#define TK 32

typedef __attribute__((ext_vector_type(8))) __bf16 bf16x8;
typedef __attribute__((ext_vector_type(4))) float f32x4;

// Order-preserving float <-> uint32 map (for atomic min/max on floats)
__device__ __forceinline__ unsigned int enc_f32(float f) {
    unsigned int u = __float_as_uint(f);
    return (u & 0x80000000u) ? ~u : (u | 0x80000000u);
}
__device__ __forceinline__ float dec_f32(unsigned int e) {
    unsigned int u = (e & 0x80000000u) ? (e ^ 0x80000000u) : ~e;
    return __uint_as_float(u);
}

__device__ __forceinline__ unsigned short f2bf(float x) {
    unsigned int u = __float_as_uint(x);
    u += 0x7FFFu + ((u >> 16) & 1u);   // RNE
    return (unsigned short)(u >> 16);
}

__device__ __forceinline__ void glds16(const unsigned short* g, const unsigned char* l) {
    __builtin_amdgcn_global_load_lds((const __attribute__((address_space(1))) void*)g,
                                     (__attribute__((address_space(3))) void*)l, 16, 0, 0);
}

// ---- convert fp32 embeddings -> bf16 scratch ----
__global__ void convert_kernel(const float* __restrict__ emb, unsigned short* __restrict__ out) {
    int i = (blockIdx.x * 256 + threadIdx.x) * 4;
    float4 v = *(const float4*)(&emb[i]);
    ushort4 o;
    o.x = f2bf(v.x); o.y = f2bf(v.y); o.z = f2bf(v.z); o.w = f2bf(v.w);
    *(ushort4*)(&out[i]) = o;
}

__global__ void init_kernel(unsigned int* __restrict__ pme, unsigned int* __restrict__ nme,
                            float* __restrict__ sp, float* __restrict__ sn) {
    int i = blockIdx.x * 256 + threadIdx.x;
    if (i < B_SIZE) {
        pme[i] = 0xFF800000u;   // enc(+inf)
        nme[i] = 0x007FFFFFu;   // enc(-inf)
        sp[i] = 0.0f;
        sn[i] = 0.0f;
    }
}

// Shared GEMM body: computes acc[4][4] (f32x4 each) = 64x64 per wave of the
// 128x128 sim tile at (m0, n0). Returns with LDS labm/labn populated.
// LDS layout (bytes): As[8192] | Bs[8192]; rows of 64B (32 bf16), chunk slot
// s holds k-chunk c = s ^ ((row>>1)&3)  (16B chunks) -> 2-way bank access on
// ds_read_b128 (free) and wave-uniform-base global_load_lds staging.
#define GEMM_BODY(acc)                                                                 \
    const int tid = threadIdx.x;                                                       \
    const int lane = tid & 63;                                                         \
    const int w = tid >> 6;                                                            \
    const int wm = w >> 1, wn = w & 1;                                                 \
    const int m0 = blockIdx.y * TM;                                                    \
    const int n0 = blockIdx.x * TM;                                                    \
    __shared__ unsigned char As[TM * 64];                                              \
    __shared__ unsigned char Bs[TM * 64];                                              \
    __shared__ int labm[TM];                                                           \
    __shared__ int labn[TM];                                                           \
    if (tid < TM) labm[tid] = labels[m0 + tid];                                        \
    else          labn[tid - TM] = labels[n0 + tid - TM];                              \
    /* staging addresses: wave w stages rows [w*32, w*32+32) in 2 issues of 16 rows */ \
    const unsigned short* gA[2];                                                       \
    const unsigned short* gB[2];                                                       \
    const unsigned char* lA[2];                                                        \
    const unsigned char* lB[2];                                                        \
    _Pragma("unroll")                                                                  \
    for (int t = 0; t < 2; ++t) {                                                      \
        int r = w * 32 + t * 16 + (lane >> 2);                                         \
        int c = (lane & 3) ^ ((r >> 1) & 3);                                           \
        gA[t] = embb + (size_t)(m0 + r) * D_SIZE + c * 8;                              \
        gB[t] = embb + (size_t)(n0 + r) * D_SIZE + c * 8;                              \
        lA[t] = As + (w * 32 + t * 16) * 64;                                           \
        lB[t] = Bs + (w * 32 + t * 16) * 64;                                           \
    }                                                                                  \
    /* fragment LDS offsets (k-invariant) */                                           \
    int aoff[4], boff[4];                                                              \
    {                                                                                  \
        int q = lane >> 4;                                                             \
        _Pragma("unroll")                                                              \
        for (int f = 0; f < 4; ++f) {                                                  \
            int ra = wm * 64 + f * 16 + (lane & 15);                                   \
            int rb = wn * 64 + f * 16 + (lane & 15);                                   \
            aoff[f] = ra * 64 + ((q ^ ((ra >> 1) & 3)) * 16);                          \
            boff[f] = rb * 64 + ((q ^ ((rb >> 1) & 3)) * 16);                          \
        }                                                                              \
    }                                                                                  \
    _Pragma("unroll")                                                                  \
    for (int fi = 0; fi < 4; ++fi)                                                     \
        _Pragma("unroll")                                                              \
        for (int fj = 0; fj < 4; ++fj)                                                 \
            acc[fi][fj] = (f32x4){0.0f, 0.0f, 0.0f, 0.0f};                             \
    for (int k0 = 0; k0 < D_SIZE; k0 += TK) {                                          \
        _Pragma("unroll")                                                              \
        for (int t = 0; t < 2; ++t) {                                                  \
            glds16(gA[t] + k0, lA[t]);                                                 \
            glds16(gB[t] + k0, lB[t]);                                                 \
        }                                                                              \
        __syncthreads();                                                               \
        bf16x8 af[4], bfr[4];                                                          \
        _Pragma("unroll")                                                              \
        for (int f = 0; f < 4; ++f) {                                                  \
            af[f]  = __builtin_bit_cast(bf16x8, *(const uint4*)(As + aoff[f]));        \
            bfr[f] = __builtin_bit_cast(bf16x8, *(const uint4*)(Bs + boff[f]));        \
        }                                                                              \
        _Pragma("unroll")                                                              \
        for (int fi = 0; fi < 4; ++fi)                                                 \
            _Pragma("unroll")                                                          \
            for (int fj = 0; fj < 4; ++fj)                                             \
                acc[fi][fj] = __builtin_amdgcn_mfma_f32_16x16x32_bf16(                 \
                    af[fi], bfr[fj], acc[fi][fj], 0, 0, 0);                            \
        __syncthreads();                                                               \
    }

// ---- Pass 1: per-row pos_min / neg_max ----
// C/D layout (16x16x32): col = lane&15, row = (lane>>4)*4 + reg  [m89/m91]
__global__ __launch_bounds__(256) void pass1_kernel(
    const unsigned short* __restrict__ embb, const int* __restrict__ labels,
    unsigned int* __restrict__ pos_min_enc, unsigned int* __restrict__ neg_max_enc)
{
    f32x4 acc[4][4];
    GEMM_BODY(acc)

    const int col = lane & 15;
    const int quad = lane >> 4;
#pragma unroll
    for (int fi = 0; fi < 4; ++fi) {
        int rl0 = wm * 64 + fi * 16 + quad * 4;
        int gi0 = m0 + rl0;
        int li[4];
#pragma unroll
        for (int r = 0; r < 4; ++r) li[r] = labm[rl0 + r];
        float mn[4], mx[4];
#pragma unroll
        for (int r = 0; r < 4; ++r) { mn[r] = __builtin_inff(); mx[r] = -__builtin_inff(); }
#pragma unroll
        for (int fj = 0; fj < 4; ++fj) {
            int cl = wn * 64 + fj * 16 + col;
            int gj = n0 + cl;
            int lj = labn[cl];
#pragma unroll
            for (int r = 0; r < 4; ++r) {
                float s = acc[fi][fj][r];
                if (gi0 + r != gj) {
                    if (li[r] == lj) mn[r] = fminf(mn[r], s);
                    else             mx[r] = fmaxf(mx[r], s);
                }
            }
        }
#pragma unroll
        for (int m = 1; m < 16; m <<= 1) {
#pragma unroll
            for (int r = 0; r < 4; ++r) {
                mn[r] = fminf(mn[r], __shfl_xor(mn[r], m, 64));
                mx[r] = fmaxf(mx[r], __shfl_xor(mx[r], m, 64));
            }
        }
        if (col == 0) {
#pragma unroll
            for (int r = 0; r < 4; ++r) {
                if (mn[r] < __builtin_inff())  atomicMin(&pos_min_enc[gi0 + r], enc_f32(mn[r]));
                if (mx[r] > -__builtin_inff()) atomicMax(&neg_max_enc[gi0 + r], enc_f32(mx[r]));
            }
        }
    }
}

// ---- Pass 2: recompute sim, accumulate masked exp-sums per row ----
__global__ __launch_bounds__(256) void pass2_kernel(
    const unsigned short* __restrict__ embb, const int* __restrict__ labels,
    const unsigned int* __restrict__ pos_min_enc, const unsigned int* __restrict__ neg_max_enc,
    float* __restrict__ sum_pos, float* __restrict__ sum_neg)
{
    f32x4 acc[4][4];
    GEMM_BODY(acc)

    const int col = lane & 15;
    const int quad = lane >> 4;
#pragma unroll
    for (int fi = 0; fi < 4; ++fi) {
        int rl0 = wm * 64 + fi * 16 + quad * 4;
        int gi0 = m0 + rl0;
        int li[4];
        float pm[4], nm[4], sp[4], sn[4];
#pragma unroll
        for (int r = 0; r < 4; ++r) {
            li[r] = labm[rl0 + r];
            pm[r] = dec_f32(pos_min_enc[gi0 + r]);
            nm[r] = dec_f32(neg_max_enc[gi0 + r]);
            sp[r] = 0.0f; sn[r] = 0.0f;
        }
#pragma unroll
        for (int fj = 0; fj < 4; ++fj) {
            int cl = wn * 64 + fj * 16 + col;
            int gj = n0 + cl;
            int lj = labn[cl];
#pragma unroll
            for (int r = 0; r < 4; ++r) {
                float s = acc[fi][fj][r];
                if (gi0 + r != gj) {
                    if (li[r] == lj) {
                        if (s - MARGIN < nm[r]) sp[r] += __expf(-ALPHA * (s - BASE));
                    } else {
                        if (s + MARGIN > pm[r]) sn[r] += __expf(BETA * (s - BASE));
                    }
                }
            }
        }
#pragma unroll
        for (int m = 1; m < 16; m <<= 1) {
#pragma unroll
            for (int r = 0; r < 4; ++r) {
                sp[r] += __shfl_xor(sp[r], m, 64);
                sn[r] += __shfl_xor(sn[r], m, 64);
            }
        }
        if (col == 0) {
#pragma unroll
            for (int r = 0; r < 4; ++r) {
                if (sp[r] > 0.0f) atomicAdd(&sum_pos[gi0 + r], sp[r]);
                if (sn[r] > 0.0f) atomicAdd(&sum_neg[gi0 + r], sn[r]);
            }
        }
    }
}

// ---- Finalize: per-row terms, masked mean ----
__global__ void finalize_kernel(const float* __restrict__ sum_pos, const float* __restrict__ sum_neg,
                                float* __restrict__ out)
{
    __shared__ float st[256];
    __shared__ float sc[256];
    const int tid = threadIdx.x;
    float tot = 0.0f, cnt = 0.0f;
    for (int i = tid; i < B_SIZE; i += 256) {
        float sp = sum_pos[i], sn = sum_neg[i];
        if (sp > 0.0f && sn > 0.0f) {
            tot += log1pf(sp) * (1.0f / ALPHA) + log1pf(sn) * (1.0f / BETA);
            cnt += 1.0f;
        }
    }
    st[tid] = tot; sc[tid] = cnt;
    __syncthreads();
    for (int s = 128; s > 0; s >>= 1) {
        if (tid < s) { st[tid] += st[tid + s]; sc[tid] += sc[tid + s]; }
        __syncthreads();
    }
    if (tid == 0) out[0] = st[0] / fmaxf(sc[0], 1.0f);
}

extern "C" void kernel_launch(void* const* d_in, const int* in_sizes, int n_in,
                              void* d_out, int out_size, void* d_ws, size_t ws_size,
                              hipStream_t stream) {
    const float* emb = (const float*)d_in[0];
    const int* labels = (const int*)d_in[1];
    float* out = (float*)d_out;

    // ws layout: bf16 emb (4 MB) | pme | nme | sum_pos | sum_neg (32 KB each)
    unsigned short* embb = (unsigned short*)d_ws;
    unsigned int* pme = (unsigned int*)(embb + (size_t)B_SIZE * D_SIZE);
    unsigned int* nme = pme + B_SIZE;
    float* sum_pos = (float*)(nme + B_SIZE);
    float* sum_neg = sum_pos + B_SIZE;

    convert_kernel<<<dim3(B_SIZE * D_SIZE / 1024), dim3(256), 0, stream>>>(emb, embb);
    init_kernel<<<dim3(B_SIZE / 256), dim3(256), 0, stream>>>(pme, nme, sum_pos, sum_neg);

    dim3 grid(B_SIZE / TM, B_SIZE / TM);
    dim3 block(256);
    pass1_kernel<<<grid, block, 0, stream>>>(embb, labels, pme, nme);
    pass2_kernel<<<grid, block, 0, stream>>>(embb, labels, pme, nme, sum_pos, sum_neg);
    finalize_kernel<<<1, dim3(256), 0, stream>>>(sum_pos, sum_neg, out);
}

// Round 3
// 200.863 us; speedup vs baseline: 5.2097x; 1.6939x over previous
//
#include <hip/hip_runtime.h>
#include <math.h>

#define B_SIZE 8192
#define D_SIZE 256
#define N_CLS 1024
#define CLS_CAP 64
#define ALPHA 2.0f
#define BETA 50.0f
#define BASE 0.5f
#define MARGIN 0.1f

// neg GEMM tiling: 128x128 block tile, BK=64, 256 threads = 4 waves (2x2 of 64x64)
#define TM 128
#define TK 64
#define NT (B_SIZE / TM)            // 64 tiles per dim
#define NBLK (NT * (NT + 1) / 2)    // 2080 triangular tiles

typedef __attribute__((ext_vector_type(8))) __bf16 bf16x8;
typedef __attribute__((ext_vector_type(4))) float f32x4;

// Order-preserving float <-> uint32 map (atomic min/max on floats)
__device__ __forceinline__ unsigned int enc_f32(float f) {
    unsigned int u = __float_as_uint(f);
    return (u & 0x80000000u) ? ~u : (u | 0x80000000u);
}
__device__ __forceinline__ float dec_f32(unsigned int e) {
    unsigned int u = (e & 0x80000000u) ? (e ^ 0x80000000u) : ~e;
    return __uint_as_float(u);
}

__device__ __forceinline__ unsigned short f2bf(float x) {
    unsigned int u = __float_as_uint(x);
    u += 0x7FFFu + ((u >> 16) & 1u);   // RNE
    return (unsigned short)(u >> 16);
}

__device__ __forceinline__ void glds16(const unsigned short* g, const unsigned char* l) {
    __builtin_amdgcn_global_load_lds((const __attribute__((address_space(1))) void*)g,
                                     (__attribute__((address_space(3))) void*)l, 16, 0, 0);
}

// exact fp32 dot of two embedding rows (L2-resident, 2 KB total)
__device__ float dot_rows(const float* __restrict__ emb, int a, int b) {
    const float4* pa = (const float4*)(emb + (size_t)a * D_SIZE);
    const float4* pb = (const float4*)(emb + (size_t)b * D_SIZE);
    float s = 0.0f;
#pragma unroll 8
    for (int k = 0; k < D_SIZE / 4; ++k) {
        float4 x = pa[k], y = pb[k];
        s += x.x * y.x + x.y * y.y + x.z * y.z + x.w * y.w;
    }
    return s;
}

// decode unordered pair index p -> (a, b), 0 <= b < a
__device__ __forceinline__ void pair_decode(int p, int& a, int& b) {
    a = (int)((1.0f + sqrtf(1.0f + 8.0f * (float)p)) * 0.5f);
    while (a * (a - 1) / 2 > p) --a;
    while ((a + 1) * a / 2 <= p) ++a;
    b = p - a * (a - 1) / 2;
}

// ---- fp32 -> bf16 conversion ----
__global__ void convert_kernel(const float* __restrict__ emb, unsigned short* __restrict__ out) {
    int i = (blockIdx.x * 256 + threadIdx.x) * 4;
    float4 v = *(const float4*)(&emb[i]);
    ushort4 o;
    o.x = f2bf(v.x); o.y = f2bf(v.y); o.z = f2bf(v.z); o.w = f2bf(v.w);
    *(ushort4*)(&out[i]) = o;
}

// ---- init: zero counters/sums, nme = enc(-inf) ----
__global__ void init_kernel(unsigned int* __restrict__ nme, float* __restrict__ sum_neg,
                            int* __restrict__ cls_cnt) {
    int i = blockIdx.x * 256 + threadIdx.x;
    if (i < B_SIZE) {
        nme[i] = 0x007FFFFFu;   // enc(-inf)
        sum_neg[i] = 0.0f;
    }
    if (i < N_CLS) cls_cnt[i] = 0;
}

// ---- scatter rows into per-class lists ----
__global__ void scatter_kernel(const int* __restrict__ labels, int* __restrict__ cls_cnt,
                               int* __restrict__ cls_rows) {
    int i = blockIdx.x * 256 + threadIdx.x;
    int lab = labels[i];
    int p = atomicAdd(&cls_cnt[lab], 1);
    if (p < CLS_CAP) cls_rows[lab * CLS_CAP + p] = i;
}

// ---- per-class exact fp32 pos_min ----
__global__ void pos_kernel(const float* __restrict__ emb, const int* __restrict__ cls_cnt,
                           const int* __restrict__ cls_rows, float* __restrict__ pos_min) {
    int cls = blockIdx.x;
    int c = min(cls_cnt[cls], CLS_CAP);
    __shared__ int rs[CLS_CAP];
    __shared__ unsigned int smin[CLS_CAP];
    int t = threadIdx.x;
    if (t < CLS_CAP) {
        smin[t] = 0xFF800000u;  // enc(+inf)
        if (t < c) rs[t] = cls_rows[cls * CLS_CAP + t];
    }
    __syncthreads();
    if (c > 1) {
        int np = c * (c - 1) / 2;
        for (int p = t; p < np; p += 256) {
            int a, b; pair_decode(p, a, b);
            float s = dot_rows(emb, rs[a], rs[b]);
            unsigned int e = enc_f32(s);
            atomicMin(&smin[a], e);
            atomicMin(&smin[b], e);
        }
    }
    __syncthreads();
    if (t < c) pos_min[rs[t]] = dec_f32(smin[t]);
}

// ---- the ONE full GEMM (triangular): neg_max + sum_neg, both sim directions ----
// C/D layout (16x16x32): col = lane&15, row = (lane>>4)*4 + reg  [m89/m91]
__global__ __launch_bounds__(256) void neg_kernel(
    const unsigned short* __restrict__ embb, const int* __restrict__ labels,
    const float* __restrict__ pos_min, unsigned int* __restrict__ nme,
    float* __restrict__ sum_neg)
{
    // triangular tile decode: bj >= bi
    int bt = blockIdx.x;
    int bi = 0, rem = bt;
    while (rem >= (NT - bi)) { rem -= (NT - bi); ++bi; }
    const int bj = bi + rem;
    const int m0 = bi * TM, n0 = bj * TM;
    const bool isdiag = (bi == bj);

    const int tid = threadIdx.x;
    const int lane = tid & 63;
    const int w = tid >> 6;
    const int wm = w >> 1, wn = w & 1;

    // LDS: rows of 128 B (64 bf16 of one K-chunk); chunk slot s of row r holds
    // global 16B-chunk c = s ^ (r&7)  -> conflict-free b128 frag reads
    __shared__ unsigned char As[TM * 128];
    __shared__ unsigned char Bs[TM * 128];
    __shared__ int labm[TM];
    __shared__ int labn[TM];

    // staging: wave w stages rows [w*32, w*32+32), 4 issues x 8 rows x 16B-chunks
    const unsigned short* gA[4];
    const unsigned short* gB[4];
    const unsigned char* lA[4];
    const unsigned char* lB[4];
#pragma unroll
    for (int s = 0; s < 4; ++s) {
        int r = w * 32 + s * 8 + (lane >> 3);
        int c = (lane & 7) ^ (r & 7);
        gA[s] = embb + (size_t)(m0 + r) * D_SIZE + c * 8;
        gB[s] = embb + (size_t)(n0 + r) * D_SIZE + c * 8;
        lA[s] = As + (w * 32 + s * 8) * 128;
        lB[s] = Bs + (w * 32 + s * 8) * 128;
    }
    // prefetch k-chunk 0 immediately
#pragma unroll
    for (int s = 0; s < 4; ++s) { glds16(gA[s], lA[s]); glds16(gB[s], lB[s]); }

    if (tid < TM) labm[tid] = labels[m0 + tid];
    else          labn[tid - TM] = labels[n0 + tid - TM];

    const int col = lane & 15;
    const int quad = lane >> 4;
    int abase[4], bbase[4], ra7[4], rb7[4];
#pragma unroll
    for (int f = 0; f < 4; ++f) {
        int ra = wm * 64 + f * 16 + col;
        int rb = wn * 64 + f * 16 + col;
        abase[f] = ra * 128; ra7[f] = ra & 7;
        bbase[f] = rb * 128; rb7[f] = rb & 7;
    }

    f32x4 acc[4][4];
#pragma unroll
    for (int fi = 0; fi < 4; ++fi)
#pragma unroll
        for (int fj = 0; fj < 4; ++fj)
            acc[fi][fj] = (f32x4){0.0f, 0.0f, 0.0f, 0.0f};

    for (int k0 = 0; k0 < D_SIZE; k0 += TK) {
        __syncthreads();   // staging of this chunk complete (barrier drains vmcnt)
        bf16x8 af[2][4], bf[2][4];
#pragma unroll
        for (int kk = 0; kk < 2; ++kk)
#pragma unroll
            for (int f = 0; f < 4; ++f) {
                af[kk][f] = __builtin_bit_cast(bf16x8,
                    *(const uint4*)(As + abase[f] + (((kk * 4 + quad) ^ ra7[f]) * 16)));
                bf[kk][f] = __builtin_bit_cast(bf16x8,
                    *(const uint4*)(Bs + bbase[f] + (((kk * 4 + quad) ^ rb7[f]) * 16)));
            }
        __syncthreads();   // all reads done before overwrite
        if (k0 + TK < D_SIZE) {
#pragma unroll
            for (int s = 0; s < 4; ++s) {
                glds16(gA[s] + k0 + TK, lA[s]);
                glds16(gB[s] + k0 + TK, lB[s]);
            }
        }
#pragma unroll
        for (int kk = 0; kk < 2; ++kk)
#pragma unroll
            for (int fi = 0; fi < 4; ++fi)
#pragma unroll
                for (int fj = 0; fj < 4; ++fj)
                    acc[fi][fj] = __builtin_amdgcn_mfma_f32_16x16x32_bf16(
                        af[kk][fi], bf[kk][fj], acc[fi][fj], 0, 0, 0);
    }

    // ---- epilogue: both sim directions per element, one exp each ----
    int ljv[4]; float pmc[4], nsn[4], nmx[4];
#pragma unroll
    for (int fj = 0; fj < 4; ++fj) {
        int cl = wn * 64 + fj * 16 + col;
        ljv[fj] = labn[cl];
        pmc[fj] = pos_min[n0 + cl];
        nsn[fj] = 0.0f;
        nmx[fj] = -__builtin_inff();
    }

#pragma unroll
    for (int fi = 0; fi < 4; ++fi) {
        int rl0 = wm * 64 + fi * 16 + quad * 4;
        int gi0 = m0 + rl0;
        int lir[4]; float pmr[4], msn[4], mmx[4];
#pragma unroll
        for (int r = 0; r < 4; ++r) {
            lir[r] = labm[rl0 + r];
            pmr[r] = pos_min[gi0 + r];
            msn[r] = 0.0f;
            mmx[r] = -__builtin_inff();
        }
#pragma unroll
        for (int fj = 0; fj < 4; ++fj) {
#pragma unroll
            for (int r = 0; r < 4; ++r) {
                float s = acc[fi][fj][r];
                if (lir[r] != ljv[fj]) {
                    float e = __expf(BETA * (s - BASE));
                    mmx[r] = fmaxf(mmx[r], s);
                    if (s + MARGIN > pmr[r]) msn[r] += e;
                    nmx[fj] = fmaxf(nmx[fj], s);
                    if (s + MARGIN > pmc[fj]) nsn[fj] += e;
                }
            }
        }
        // m-side: reduce across the 16 col-lanes
#pragma unroll
        for (int m = 1; m < 16; m <<= 1) {
#pragma unroll
            for (int r = 0; r < 4; ++r) {
                msn[r] += __shfl_xor(msn[r], m, 64);
                mmx[r] = fmaxf(mmx[r], __shfl_xor(mmx[r], m, 64));
            }
        }
        if (col == 0) {
#pragma unroll
            for (int r = 0; r < 4; ++r) {
                if (msn[r] > 0.0f) atomicAdd(&sum_neg[gi0 + r], msn[r]);
                if (mmx[r] > -__builtin_inff()) atomicMax(&nme[gi0 + r], enc_f32(mmx[r]));
            }
        }
    }
    // n-side: reduce across quads (off-diagonal tiles only; diag tile already
    // contains both orientations of each pair)
    if (!isdiag) {
#pragma unroll
        for (int m = 16; m < 64; m <<= 1) {
#pragma unroll
            for (int fj = 0; fj < 4; ++fj) {
                nsn[fj] += __shfl_xor(nsn[fj], m, 64);
                nmx[fj] = fmaxf(nmx[fj], __shfl_xor(nmx[fj], m, 64));
            }
        }
        if (quad == 0) {
#pragma unroll
            for (int fj = 0; fj < 4; ++fj) {
                int gj = n0 + wn * 64 + fj * 16 + col;
                if (nsn[fj] > 0.0f) atomicAdd(&sum_neg[gj], nsn[fj]);
                if (nmx[fj] > -__builtin_inff()) atomicMax(&nme[gj], enc_f32(nmx[fj]));
            }
        }
    }
}

// ---- per-class sum_pos using neg_max ----
__global__ void posum_kernel(const float* __restrict__ emb, const int* __restrict__ cls_cnt,
                             const int* __restrict__ cls_rows, const unsigned int* __restrict__ nme,
                             float* __restrict__ sum_pos) {
    int cls = blockIdx.x;
    int c = min(cls_cnt[cls], CLS_CAP);
    __shared__ int rs[CLS_CAP];
    __shared__ float ssum[CLS_CAP];
    __shared__ float snm[CLS_CAP];
    int t = threadIdx.x;
    if (t < CLS_CAP) {
        ssum[t] = 0.0f;
        if (t < c) rs[t] = cls_rows[cls * CLS_CAP + t];
    }
    __syncthreads();
    if (t < c) snm[t] = dec_f32(nme[rs[t]]);
    __syncthreads();
    if (c > 1) {
        int np = c * (c - 1) / 2;
        for (int p = t; p < np; p += 256) {
            int a, b; pair_decode(p, a, b);
            float s = dot_rows(emb, rs[a], rs[b]);
            float e = __expf(-ALPHA * (s - BASE));
            if (s - MARGIN < snm[a]) atomicAdd(&ssum[a], e);
            if (s - MARGIN < snm[b]) atomicAdd(&ssum[b], e);
        }
    }
    __syncthreads();
    if (t < c) sum_pos[rs[t]] = ssum[t];
}

// ---- finalize: per-row terms, masked mean ----
__global__ void finalize_kernel(const float* __restrict__ sum_pos, const float* __restrict__ sum_neg,
                                float* __restrict__ out)
{
    __shared__ float st[256];
    __shared__ float sc[256];
    const int tid = threadIdx.x;
    float tot = 0.0f, cnt = 0.0f;
    for (int i = tid; i < B_SIZE; i += 256) {
        float sp = sum_pos[i], sn = sum_neg[i];
        if (sp > 0.0f && sn > 0.0f) {
            tot += log1pf(sp) * (1.0f / ALPHA) + log1pf(sn) * (1.0f / BETA);
            cnt += 1.0f;
        }
    }
    st[tid] = tot; sc[tid] = cnt;
    __syncthreads();
    for (int s = 128; s > 0; s >>= 1) {
        if (tid < s) { st[tid] += st[tid + s]; sc[tid] += sc[tid + s]; }
        __syncthreads();
    }
    if (tid == 0) out[0] = st[0] / fmaxf(sc[0], 1.0f);
}

extern "C" void kernel_launch(void* const* d_in, const int* in_sizes, int n_in,
                              void* d_out, int out_size, void* d_ws, size_t ws_size,
                              hipStream_t stream) {
    const float* emb = (const float*)d_in[0];
    const int* labels = (const int*)d_in[1];
    float* out = (float*)d_out;

    // ws layout: bf16 emb (4 MB) | pos_min | nme | sum_pos | sum_neg (32 KB each)
    //            | cls_cnt (4 KB) | cls_rows (256 KB)
    unsigned short* embb = (unsigned short*)d_ws;
    float* pos_min = (float*)(embb + (size_t)B_SIZE * D_SIZE);
    unsigned int* nme = (unsigned int*)(pos_min + B_SIZE);
    float* sum_pos = (float*)(nme + B_SIZE);
    float* sum_neg = sum_pos + B_SIZE;
    int* cls_cnt = (int*)(sum_neg + B_SIZE);
    int* cls_rows = cls_cnt + N_CLS;

    convert_kernel<<<dim3(B_SIZE * D_SIZE / 1024), dim3(256), 0, stream>>>(emb, embb);
    init_kernel<<<dim3(B_SIZE / 256), dim3(256), 0, stream>>>(nme, sum_neg, cls_cnt);
    scatter_kernel<<<dim3(B_SIZE / 256), dim3(256), 0, stream>>>(labels, cls_cnt, cls_rows);
    pos_kernel<<<dim3(N_CLS), dim3(256), 0, stream>>>(emb, cls_cnt, cls_rows, pos_min);
    neg_kernel<<<dim3(NBLK), dim3(256), 0, stream>>>(embb, labels, pos_min, nme, sum_neg);
    posum_kernel<<<dim3(N_CLS), dim3(256), 0, stream>>>(emb, cls_cnt, cls_rows, nme, sum_pos);
    finalize_kernel<<<1, dim3(256), 0, stream>>>(sum_pos, sum_neg, out);
}

// Round 4
// 185.540 us; speedup vs baseline: 5.6400x; 1.0826x over previous
//
#include <hip/hip_runtime.h>
#include <math.h>

#define B_SIZE 8192
#define D_SIZE 256
#define N_CLS 1024
#define CLS_CAP 64
#define ALPHA 2.0f
#define BETA 50.0f
#define BASE 0.5f
#define MARGIN 0.1f

// neg GEMM tiling: 128x128 block tile, BK=64, 256 threads = 4 waves (2x2 of 64x64)
#define TM 128
#define TK 64
#define NT (B_SIZE / TM)            // 64 tiles per dim
#define NBLK (NT * (NT + 1) / 2)    // 2080 triangular tiles

typedef __attribute__((ext_vector_type(8))) __bf16 bf16x8;
typedef __attribute__((ext_vector_type(4))) float f32x4;

// Order-preserving float <-> uint32 map (LDS atomic min on floats)
__device__ __forceinline__ unsigned int enc_f32(float f) {
    unsigned int u = __float_as_uint(f);
    return (u & 0x80000000u) ? ~u : (u | 0x80000000u);
}
__device__ __forceinline__ float dec_f32(unsigned int e) {
    unsigned int u = (e & 0x80000000u) ? (e ^ 0x80000000u) : ~e;
    return __uint_as_float(u);
}

__device__ __forceinline__ unsigned short f2bf(float x) {
    unsigned int u = __float_as_uint(x);
    u += 0x7FFFu + ((u >> 16) & 1u);   // RNE
    return (unsigned short)(u >> 16);
}

__device__ __forceinline__ void glds16(const unsigned short* g, const unsigned char* l) {
    __builtin_amdgcn_global_load_lds((const __attribute__((address_space(1))) void*)g,
                                     (__attribute__((address_space(3))) void*)l, 16, 0, 0);
}

// exact fp32 dot of two embedding rows (L2-resident)
__device__ float dot_rows(const float* __restrict__ emb, int a, int b) {
    const float4* pa = (const float4*)(emb + (size_t)a * D_SIZE);
    const float4* pb = (const float4*)(emb + (size_t)b * D_SIZE);
    float s = 0.0f;
#pragma unroll 8
    for (int k = 0; k < D_SIZE / 4; ++k) {
        float4 x = pa[k], y = pb[k];
        s += x.x * y.x + x.y * y.y + x.z * y.z + x.w * y.w;
    }
    return s;
}

// decode unordered pair index p -> (a, b), 0 <= b < a
__device__ __forceinline__ void pair_decode(int p, int& a, int& b) {
    a = (int)((1.0f + sqrtf(1.0f + 8.0f * (float)p)) * 0.5f);
    while (a * (a - 1) / 2 > p) --a;
    while ((a + 1) * a / 2 <= p) ++a;
    b = p - a * (a - 1) / 2;
}

// ---- prep: fp32 -> bf16 conversion + zero the 3 global scalars ----
__global__ void prep_kernel(const float* __restrict__ emb, unsigned short* __restrict__ out,
                            float* __restrict__ gtot, float* __restrict__ gcnt,
                            unsigned int* __restrict__ gdone) {
    int i = (blockIdx.x * 256 + threadIdx.x) * 4;
    float4 v = *(const float4*)(&emb[i]);
    ushort4 o;
    o.x = f2bf(v.x); o.y = f2bf(v.y); o.z = f2bf(v.z); o.w = f2bf(v.w);
    *(ushort4*)(&out[i]) = o;
    if (blockIdx.x == 0 && threadIdx.x == 0) {
        *gtot = 0.0f; *gcnt = 0.0f; *gdone = 0u;
    }
}

// ---- per-class exact fp32 pos_min (scans labels in-kernel) ----
__global__ void pos_kernel(const float* __restrict__ emb, const int* __restrict__ labels,
                           float* __restrict__ pos_min) {
    int cls = blockIdx.x;
    __shared__ int rs[CLS_CAP];
    __shared__ unsigned int smin[CLS_CAP];
    __shared__ int lcnt;
    int t = threadIdx.x;
    if (t == 0) lcnt = 0;
    if (t < CLS_CAP) smin[t] = 0xFF800000u;  // enc(+inf)
    __syncthreads();
    for (int i = t; i < B_SIZE; i += 256) {
        if (labels[i] == cls) {
            int p = atomicAdd(&lcnt, 1);
            if (p < CLS_CAP) rs[p] = i;
        }
    }
    __syncthreads();
    int c = min(lcnt, CLS_CAP);
    if (c > 1) {
        int np = c * (c - 1) / 2;
        for (int p = t; p < np; p += 256) {
            int a, b; pair_decode(p, a, b);
            unsigned int e = enc_f32(dot_rows(emb, rs[a], rs[b]));
            atomicMin(&smin[a], e);
            atomicMin(&smin[b], e);
        }
    }
    __syncthreads();
    if (t < c) pos_min[rs[t]] = dec_f32(smin[t]);
}

// ---- the ONE GEMM (triangular tiles): per-tile neg partials, plain stores ----
// Row r (block-row bi, block-col bj) coverage of part[k][r]: m-side writes
// k=bj for bj in [bi,63], n-side writes k=bi for bi in [0,bj) -> each k in
// [0,64) written exactly once, unconditionally => no zero-init, no atomics.
// C/D layout (16x16x32): col = lane&15, row = (lane>>4)*4 + reg  [m89/m91]
__global__ __launch_bounds__(256) void neg_kernel(
    const unsigned short* __restrict__ embb, const int* __restrict__ labels,
    const float* __restrict__ pos_min,
    float* __restrict__ part_sum, float* __restrict__ part_max)
{
    // triangular tile decode: bj >= bi
    int bt = blockIdx.x;
    int bi = 0, rem = bt;
    while (rem >= (NT - bi)) { rem -= (NT - bi); ++bi; }
    const int bj = bi + rem;
    const int m0 = bi * TM, n0 = bj * TM;
    const bool isdiag = (bi == bj);

    const int tid = threadIdx.x;
    const int lane = tid & 63;
    const int w = tid >> 6;
    const int wm = w >> 1, wn = w & 1;

    // LDS rows of 128 B; chunk slot s of row r holds global 16B-chunk s^(r&7)
    __shared__ unsigned char As[TM * 128];
    __shared__ unsigned char Bs[TM * 128];
    __shared__ int labm[TM];
    __shared__ int labn[TM];

    const unsigned short* gA[4];
    const unsigned short* gB[4];
    const unsigned char* lA[4];
    const unsigned char* lB[4];
#pragma unroll
    for (int s = 0; s < 4; ++s) {
        int r = w * 32 + s * 8 + (lane >> 3);
        int c = (lane & 7) ^ (r & 7);
        gA[s] = embb + (size_t)(m0 + r) * D_SIZE + c * 8;
        gB[s] = embb + (size_t)(n0 + r) * D_SIZE + c * 8;
        lA[s] = As + (w * 32 + s * 8) * 128;
        lB[s] = Bs + (w * 32 + s * 8) * 128;
    }
#pragma unroll
    for (int s = 0; s < 4; ++s) { glds16(gA[s], lA[s]); glds16(gB[s], lB[s]); }

    if (tid < TM) labm[tid] = labels[m0 + tid];
    else          labn[tid - TM] = labels[n0 + tid - TM];

    const int col = lane & 15;
    const int quad = lane >> 4;
    int abase[4], bbase[4], ra7[4], rb7[4];
#pragma unroll
    for (int f = 0; f < 4; ++f) {
        int ra = wm * 64 + f * 16 + col;
        int rb = wn * 64 + f * 16 + col;
        abase[f] = ra * 128; ra7[f] = ra & 7;
        bbase[f] = rb * 128; rb7[f] = rb & 7;
    }

    f32x4 acc[4][4];
#pragma unroll
    for (int fi = 0; fi < 4; ++fi)
#pragma unroll
        for (int fj = 0; fj < 4; ++fj)
            acc[fi][fj] = (f32x4){0.0f, 0.0f, 0.0f, 0.0f};

    for (int k0 = 0; k0 < D_SIZE; k0 += TK) {
        __syncthreads();   // staging of this chunk complete
        bf16x8 af[2][4], bf[2][4];
#pragma unroll
        for (int kk = 0; kk < 2; ++kk)
#pragma unroll
            for (int f = 0; f < 4; ++f) {
                af[kk][f] = __builtin_bit_cast(bf16x8,
                    *(const uint4*)(As + abase[f] + (((kk * 4 + quad) ^ ra7[f]) * 16)));
                bf[kk][f] = __builtin_bit_cast(bf16x8,
                    *(const uint4*)(Bs + bbase[f] + (((kk * 4 + quad) ^ rb7[f]) * 16)));
            }
        __syncthreads();   // all reads done before overwrite
        if (k0 + TK < D_SIZE) {
#pragma unroll
            for (int s = 0; s < 4; ++s) {
                glds16(gA[s] + k0 + TK, lA[s]);
                glds16(gB[s] + k0 + TK, lB[s]);
            }
        }
#pragma unroll
        for (int kk = 0; kk < 2; ++kk)
#pragma unroll
            for (int fi = 0; fi < 4; ++fi)
#pragma unroll
                for (int fj = 0; fj < 4; ++fj)
                    acc[fi][fj] = __builtin_amdgcn_mfma_f32_16x16x32_bf16(
                        af[kk][fi], bf[kk][fj], acc[fi][fj], 0, 0, 0);
    }

    // ---- epilogue: both sim directions per element, one exp each ----
    int ljv[4]; float pmc[4], nsn[4], nmx[4];
#pragma unroll
    for (int fj = 0; fj < 4; ++fj) {
        int cl = wn * 64 + fj * 16 + col;
        ljv[fj] = labn[cl];
        pmc[fj] = pos_min[n0 + cl];
        nsn[fj] = 0.0f;
        nmx[fj] = -__builtin_inff();
    }

#pragma unroll
    for (int fi = 0; fi < 4; ++fi) {
        int rl0 = wm * 64 + fi * 16 + quad * 4;
        int gi0 = m0 + rl0;
        int lir[4]; float pmr[4], msn[4], mmx[4];
#pragma unroll
        for (int r = 0; r < 4; ++r) {
            lir[r] = labm[rl0 + r];
            pmr[r] = pos_min[gi0 + r];
            msn[r] = 0.0f;
            mmx[r] = -__builtin_inff();
        }
#pragma unroll
        for (int fj = 0; fj < 4; ++fj) {
#pragma unroll
            for (int r = 0; r < 4; ++r) {
                float s = acc[fi][fj][r];
                if (lir[r] != ljv[fj]) {
                    float e = __expf(BETA * (s - BASE));
                    mmx[r] = fmaxf(mmx[r], s);
                    if (s + MARGIN > pmr[r]) msn[r] += e;
                    nmx[fj] = fmaxf(nmx[fj], s);
                    if (s + MARGIN > pmc[fj]) nsn[fj] += e;
                }
            }
        }
        // m-side: reduce across the 16 col-lanes (xor<16 -> DPP, cheap)
#pragma unroll
        for (int m = 1; m < 16; m <<= 1) {
#pragma unroll
            for (int r = 0; r < 4; ++r) {
                msn[r] += __shfl_xor(msn[r], m, 64);
                mmx[r] = fmaxf(mmx[r], __shfl_xor(mmx[r], m, 64));
            }
        }
        if (col == 0) {
#pragma unroll
            for (int r = 0; r < 4; ++r) {
                part_sum[(size_t)bj * B_SIZE + gi0 + r] = msn[r];
                part_max[(size_t)bj * B_SIZE + gi0 + r] = mmx[r];
            }
        }
    }
    // n-side (off-diagonal only; diag's n-slot is its own m-side write)
    if (!isdiag) {
#pragma unroll
        for (int m = 16; m < 64; m <<= 1) {
#pragma unroll
            for (int fj = 0; fj < 4; ++fj) {
                nsn[fj] += __shfl_xor(nsn[fj], m, 64);
                nmx[fj] = fmaxf(nmx[fj], __shfl_xor(nmx[fj], m, 64));
            }
        }
        if (quad == 0) {
#pragma unroll
            for (int fj = 0; fj < 4; ++fj) {
                int gj = n0 + wn * 64 + fj * 16 + col;
                part_sum[(size_t)bi * B_SIZE + gj] = nsn[fj];
                part_max[(size_t)bi * B_SIZE + gj] = nmx[fj];
            }
        }
    }
}

// ---- per-class: reduce neg partials, pair-dots for sum_pos, fused finalize ----
__global__ void posum_final_kernel(const float* __restrict__ emb, const int* __restrict__ labels,
                                   const float* __restrict__ part_sum, const float* __restrict__ part_max,
                                   float* __restrict__ gtot, float* __restrict__ gcnt,
                                   unsigned int* __restrict__ gdone, float* __restrict__ out) {
    int cls = blockIdx.x;
    __shared__ int rs[CLS_CAP];
    __shared__ float snm[CLS_CAP];
    __shared__ float sneg[CLS_CAP];
    __shared__ float ssum[CLS_CAP];
    __shared__ int lcnt;
    __shared__ float red[256];
    __shared__ float redc[256];
    int t = threadIdx.x;
    if (t == 0) lcnt = 0;
    if (t < CLS_CAP) ssum[t] = 0.0f;
    __syncthreads();
    for (int i = t; i < B_SIZE; i += 256) {
        if (labels[i] == cls) {
            int p = atomicAdd(&lcnt, 1);
            if (p < CLS_CAP) rs[p] = i;
        }
    }
    __syncthreads();
    int c = min(lcnt, CLS_CAP);
    // reduce the 64 neg partials for this class's rows
    if (t < c) {
        int row = rs[t];
        float s = 0.0f, m = -__builtin_inff();
#pragma unroll 8
        for (int k = 0; k < NT; ++k) {
            s += part_sum[(size_t)k * B_SIZE + row];
            m = fmaxf(m, part_max[(size_t)k * B_SIZE + row]);
        }
        sneg[t] = s;
        snm[t] = m;
    }
    __syncthreads();
    if (c > 1) {
        int np = c * (c - 1) / 2;
        for (int p = t; p < np; p += 256) {
            int a, b; pair_decode(p, a, b);
            float s = dot_rows(emb, rs[a], rs[b]);
            float e = __expf(-ALPHA * (s - BASE));
            if (s - MARGIN < snm[a]) atomicAdd(&ssum[a], e);
            if (s - MARGIN < snm[b]) atomicAdd(&ssum[b], e);
        }
    }
    __syncthreads();
    float term = 0.0f, valid = 0.0f;
    if (t < c) {
        float sp = ssum[t], sn = sneg[t];
        if (sp > 0.0f && sn > 0.0f) {
            term = log1pf(sp) * (1.0f / ALPHA) + log1pf(sn) * (1.0f / BETA);
            valid = 1.0f;
        }
    }
    red[t] = term; redc[t] = valid;
    __syncthreads();
    for (int s = 128; s > 0; s >>= 1) {
        if (t < s) { red[t] += red[t + s]; redc[t] += redc[t + s]; }
        __syncthreads();
    }
    if (t == 0) {
        atomicAdd(gtot, red[0]);
        atomicAdd(gcnt, redc[0]);
        __threadfence();
        unsigned int tk = atomicAdd(gdone, 1u);
        if (tk == N_CLS - 1) {
            float T = __hip_atomic_load(gtot, __ATOMIC_RELAXED, __HIP_MEMORY_SCOPE_AGENT);
            float C = __hip_atomic_load(gcnt, __ATOMIC_RELAXED, __HIP_MEMORY_SCOPE_AGENT);
            out[0] = T / fmaxf(C, 1.0f);
        }
    }
}

extern "C" void kernel_launch(void* const* d_in, const int* in_sizes, int n_in,
                              void* d_out, int out_size, void* d_ws, size_t ws_size,
                              hipStream_t stream) {
    const float* emb = (const float*)d_in[0];
    const int* labels = (const int*)d_in[1];
    float* out = (float*)d_out;

    // ws layout: bf16 emb (4 MB) | pos_min (32 KB) | part_sum (2 MB) |
    //            part_max (2 MB) | gtot, gcnt, gdone
    unsigned short* embb = (unsigned short*)d_ws;
    float* pos_min = (float*)(embb + (size_t)B_SIZE * D_SIZE);
    float* part_sum = pos_min + B_SIZE;
    float* part_max = part_sum + (size_t)NT * B_SIZE;
    float* gtot = part_max + (size_t)NT * B_SIZE;
    float* gcnt = gtot + 1;
    unsigned int* gdone = (unsigned int*)(gcnt + 1);

    prep_kernel<<<dim3(B_SIZE * D_SIZE / 1024), dim3(256), 0, stream>>>(emb, embb, gtot, gcnt, gdone);
    pos_kernel<<<dim3(N_CLS), dim3(256), 0, stream>>>(emb, labels, pos_min);
    neg_kernel<<<dim3(NBLK), dim3(256), 0, stream>>>(embb, labels, pos_min, part_sum, part_max);
    posum_final_kernel<<<dim3(N_CLS), dim3(256), 0, stream>>>(emb, labels, part_sum, part_max,
                                                              gtot, gcnt, gdone, out);
}

// Round 5
// 177.581 us; speedup vs baseline: 5.8927x; 1.0448x over previous
//
#include <hip/hip_runtime.h>
#include <math.h>

#define B_SIZE 8192
#define D_SIZE 256
#define N_CLS 1024
#define CLS_CAP 64
#define PCAP 256
#define ALPHA 2.0f
#define BETA 50.0f
#define BASE 0.5f
#define MARGIN 0.1f

// neg GEMM tiling: 128x128 block tile, BK=32, 256 threads = 4 waves (2x2 of 64x64)
// LDS ~17 KB -> ~6 blocks/CU (VGPR-capped), vs round-4's 33.8 KB / ~3-4 blocks.
#define TM 128
#define TK 32
#define NT (B_SIZE / TM)            // 64 tiles per dim
#define NBLK (NT * (NT + 1) / 2)    // 2080 triangular tiles

typedef __attribute__((ext_vector_type(8))) __bf16 bf16x8;
typedef __attribute__((ext_vector_type(4))) float f32x4;

__device__ __forceinline__ unsigned int enc_f32(float f) {
    unsigned int u = __float_as_uint(f);
    return (u & 0x80000000u) ? ~u : (u | 0x80000000u);
}
__device__ __forceinline__ float dec_f32(unsigned int e) {
    unsigned int u = (e & 0x80000000u) ? (e ^ 0x80000000u) : ~e;
    return __uint_as_float(u);
}

__device__ __forceinline__ unsigned short f2bf(float x) {
    unsigned int u = __float_as_uint(x);
    u += 0x7FFFu + ((u >> 16) & 1u);   // RNE
    return (unsigned short)(u >> 16);
}

__device__ __forceinline__ void glds16(const unsigned short* g, const unsigned char* l) {
    __builtin_amdgcn_global_load_lds((const __attribute__((address_space(1))) void*)g,
                                     (__attribute__((address_space(3))) void*)l, 16, 0, 0);
}

// decode unordered pair index p -> (a, b), 0 <= b < a
__device__ __forceinline__ void pair_decode(int p, int& a, int& b) {
    a = (int)((1.0f + sqrtf(1.0f + 8.0f * (float)p)) * 0.5f);
    while (a * (a - 1) / 2 > p) --a;
    while ((a + 1) * a / 2 <= p) ++a;
    b = p - a * (a - 1) / 2;
}

// ---- prep: fp32 -> bf16 conversion + zero the 3 global scalars ----
__global__ void prep_kernel(const float* __restrict__ emb, unsigned short* __restrict__ out,
                            float* __restrict__ gtot, float* __restrict__ gcnt,
                            unsigned int* __restrict__ gdone) {
    int i = (blockIdx.x * 256 + threadIdx.x) * 4;
    float4 v = *(const float4*)(&emb[i]);
    ushort4 o;
    o.x = f2bf(v.x); o.y = f2bf(v.y); o.z = f2bf(v.z); o.w = f2bf(v.w);
    *(ushort4*)(&out[i]) = o;
    if (blockIdx.x == 0 && threadIdx.x == 0) {
        *gtot = 0.0f; *gcnt = 0.0f; *gdone = 0u;
    }
}

// ---- per-class: build row list, exact fp32 pair sims (8 lanes/pair),
//      pos_min; cache sims + row list for posum ----
__global__ __launch_bounds__(256) void pos_kernel(
    const float* __restrict__ emb, const int* __restrict__ labels,
    float* __restrict__ pos_min, float* __restrict__ psims,
    int* __restrict__ cls_cnt, int* __restrict__ cls_rows) {
    int cls = blockIdx.x;
    __shared__ int rs[CLS_CAP];
    __shared__ unsigned int smin[CLS_CAP];
    __shared__ int lcnt;
    int t = threadIdx.x;
    if (t == 0) lcnt = 0;
    if (t < CLS_CAP) smin[t] = 0xFF800000u;  // enc(+inf)
    __syncthreads();
    const int4* lab4 = (const int4*)labels;
    for (int i = t; i < B_SIZE / 4; i += 256) {
        int4 L = lab4[i];
        if (L.x == cls) { int p = atomicAdd(&lcnt, 1); if (p < CLS_CAP) rs[p] = 4 * i; }
        if (L.y == cls) { int p = atomicAdd(&lcnt, 1); if (p < CLS_CAP) rs[p] = 4 * i + 1; }
        if (L.z == cls) { int p = atomicAdd(&lcnt, 1); if (p < CLS_CAP) rs[p] = 4 * i + 2; }
        if (L.w == cls) { int p = atomicAdd(&lcnt, 1); if (p < CLS_CAP) rs[p] = 4 * i + 3; }
    }
    __syncthreads();
    int c = min(lcnt, CLS_CAP);
    if (t == 0) cls_cnt[cls] = c;
    if (t < c) cls_rows[cls * CLS_CAP + t] = rs[t];
    int np = c * (c - 1) / 2;
    for (int base = 0; base < np * 8; base += 256) {
        int slot = base + t;
        if (slot < np * 8) {
            int p = slot >> 3, l = slot & 7;   // 8 aligned lanes per pair
            int a, b; pair_decode(p, a, b);
            const float4* pa = (const float4*)(emb + (size_t)rs[a] * D_SIZE) + l * 8;
            const float4* pb = (const float4*)(emb + (size_t)rs[b] * D_SIZE) + l * 8;
            float s = 0.0f;
#pragma unroll
            for (int k = 0; k < 8; ++k) {
                float4 x = pa[k], y = pb[k];
                s = fmaf(x.x, y.x, fmaf(x.y, y.y, fmaf(x.z, y.z, fmaf(x.w, y.w, s))));
            }
            s += __shfl_xor(s, 1, 64);
            s += __shfl_xor(s, 2, 64);
            s += __shfl_xor(s, 4, 64);
            if (l == 0) {
                if (p < PCAP) psims[cls * PCAP + p] = s;
                unsigned int e = enc_f32(s);
                atomicMin(&smin[a], e);
                atomicMin(&smin[b], e);
            }
        }
    }
    __syncthreads();
    if (t < c) pos_min[rs[t]] = dec_f32(smin[t]);
}

// ---- the ONE GEMM (triangular tiles): per-tile neg partials, plain stores ----
// part[row*NT + k]: m-side writes k=bj (bj>=bi), n-side k=bi (bi<bj) -> each
// k written exactly once, unconditionally => no zero-init, no atomics.
// C/D layout (16x16x32): col = lane&15, row = (lane>>4)*4 + reg  [m89/m91]
__global__ __launch_bounds__(256) void neg_kernel(
    const unsigned short* __restrict__ embb, const int* __restrict__ labels,
    const float* __restrict__ pos_min,
    float* __restrict__ part_sum, float* __restrict__ part_max)
{
    // triangular tile decode: bj >= bi
    int bt = blockIdx.x;
    int bi = 0, rem = bt;
    while (rem >= (NT - bi)) { rem -= (NT - bi); ++bi; }
    const int bj = bi + rem;
    const int m0 = bi * TM, n0 = bj * TM;
    const bool isdiag = (bi == bj);

    const int tid = threadIdx.x;
    const int lane = tid & 63;
    const int w = tid >> 6;
    const int wm = w >> 1, wn = w & 1;

    // LDS rows of 64 B (32 bf16); chunk slot s of row r holds 16B-chunk s^((r>>1)&3)
    __shared__ unsigned char As[TM * 64];
    __shared__ unsigned char Bs[TM * 64];
    __shared__ int labm[TM];
    __shared__ int labn[TM];

    const unsigned short* gA[2];
    const unsigned short* gB[2];
    const unsigned char* lA[2];
    const unsigned char* lB[2];
#pragma unroll
    for (int s = 0; s < 2; ++s) {
        int r = w * 32 + s * 16 + (lane >> 2);
        int c = (lane & 3) ^ ((r >> 1) & 3);
        gA[s] = embb + (size_t)(m0 + r) * D_SIZE + c * 8;
        gB[s] = embb + (size_t)(n0 + r) * D_SIZE + c * 8;
        lA[s] = As + (w * 32 + s * 16) * 64;
        lB[s] = Bs + (w * 32 + s * 16) * 64;
    }
    // prefetch k-chunk 0
#pragma unroll
    for (int s = 0; s < 2; ++s) { glds16(gA[s], lA[s]); glds16(gB[s], lB[s]); }

    if (tid < TM) labm[tid] = labels[m0 + tid];
    else          labn[tid - TM] = labels[n0 + tid - TM];

    const int col = lane & 15;
    const int quad = lane >> 4;
    int aoff[4], boff[4];
#pragma unroll
    for (int f = 0; f < 4; ++f) {
        int ra = wm * 64 + f * 16 + col;
        int rb = wn * 64 + f * 16 + col;
        aoff[f] = ra * 64 + ((quad ^ ((ra >> 1) & 3)) * 16);
        boff[f] = rb * 64 + ((quad ^ ((rb >> 1) & 3)) * 16);
    }

    f32x4 acc[4][4];
#pragma unroll
    for (int fi = 0; fi < 4; ++fi)
#pragma unroll
        for (int fj = 0; fj < 4; ++fj)
            acc[fi][fj] = (f32x4){0.0f, 0.0f, 0.0f, 0.0f};

    for (int k0 = 0; k0 < D_SIZE; k0 += TK) {
        __syncthreads();   // staging of this chunk complete (barrier drains vmcnt)
        bf16x8 af[4], bf[4];
#pragma unroll
        for (int f = 0; f < 4; ++f) {
            af[f] = __builtin_bit_cast(bf16x8, *(const uint4*)(As + aoff[f]));
            bf[f] = __builtin_bit_cast(bf16x8, *(const uint4*)(Bs + boff[f]));
        }
        __syncthreads();   // all reads done before overwrite
        if (k0 + TK < D_SIZE) {
#pragma unroll
            for (int s = 0; s < 2; ++s) {
                glds16(gA[s] + k0 + TK, lA[s]);
                glds16(gB[s] + k0 + TK, lB[s]);
            }
        }
#pragma unroll
        for (int fi = 0; fi < 4; ++fi)
#pragma unroll
            for (int fj = 0; fj < 4; ++fj)
                acc[fi][fj] = __builtin_amdgcn_mfma_f32_16x16x32_bf16(
                    af[fi], bf[fj], acc[fi][fj], 0, 0, 0);
    }

    // ---- epilogue: both sim directions per element, one exp each ----
    int ljv[4]; float pmc[4], nsn[4], nmx[4];
#pragma unroll
    for (int fj = 0; fj < 4; ++fj) {
        int cl = wn * 64 + fj * 16 + col;
        ljv[fj] = labn[cl];
        pmc[fj] = pos_min[n0 + cl];
        nsn[fj] = 0.0f;
        nmx[fj] = -__builtin_inff();
    }

#pragma unroll
    for (int fi = 0; fi < 4; ++fi) {
        int rl0 = wm * 64 + fi * 16 + quad * 4;
        int gi0 = m0 + rl0;
        int lir[4]; float pmr[4], msn[4], mmx[4];
#pragma unroll
        for (int r = 0; r < 4; ++r) {
            lir[r] = labm[rl0 + r];
            pmr[r] = pos_min[gi0 + r];
            msn[r] = 0.0f;
            mmx[r] = -__builtin_inff();
        }
#pragma unroll
        for (int fj = 0; fj < 4; ++fj) {
#pragma unroll
            for (int r = 0; r < 4; ++r) {
                float s = acc[fi][fj][r];
                if (lir[r] != ljv[fj]) {
                    float e = __expf(BETA * (s - BASE));
                    mmx[r] = fmaxf(mmx[r], s);
                    if (s + MARGIN > pmr[r]) msn[r] += e;
                    nmx[fj] = fmaxf(nmx[fj], s);
                    if (s + MARGIN > pmc[fj]) nsn[fj] += e;
                }
            }
        }
        // m-side: reduce across the 16 col-lanes
#pragma unroll
        for (int m = 1; m < 16; m <<= 1) {
#pragma unroll
            for (int r = 0; r < 4; ++r) {
                msn[r] += __shfl_xor(msn[r], m, 64);
                mmx[r] = fmaxf(mmx[r], __shfl_xor(mmx[r], m, 64));
            }
        }
        if (col == 0) {
#pragma unroll
            for (int r = 0; r < 4; ++r) {
                part_sum[(size_t)(gi0 + r) * NT + bj] = msn[r];
                part_max[(size_t)(gi0 + r) * NT + bj] = mmx[r];
            }
        }
    }
    // n-side (off-diagonal only; diag's slot is its own m-side write)
    if (!isdiag) {
#pragma unroll
        for (int m = 16; m < 64; m <<= 1) {
#pragma unroll
            for (int fj = 0; fj < 4; ++fj) {
                nsn[fj] += __shfl_xor(nsn[fj], m, 64);
                nmx[fj] = fmaxf(nmx[fj], __shfl_xor(nmx[fj], m, 64));
            }
        }
        if (quad == 0) {
#pragma unroll
            for (int fj = 0; fj < 4; ++fj) {
                int gj = n0 + wn * 64 + fj * 16 + col;
                part_sum[(size_t)gj * NT + bi] = nsn[fj];
                part_max[(size_t)gj * NT + bi] = nmx[fj];
            }
        }
    }
}

// ---- per-class: reduce neg partials (vectorized), sum_pos from cached sims,
//      fused finalize ----
__global__ __launch_bounds__(256) void posum_final_kernel(
    const float* __restrict__ emb, const int* __restrict__ cls_cnt,
    const int* __restrict__ cls_rows, const float* __restrict__ psims,
    const float* __restrict__ part_sum, const float* __restrict__ part_max,
    float* __restrict__ gtot, float* __restrict__ gcnt,
    unsigned int* __restrict__ gdone, float* __restrict__ out) {
    int cls = blockIdx.x;
    __shared__ int rs[CLS_CAP];
    __shared__ float snm[CLS_CAP];
    __shared__ float sneg[CLS_CAP];
    __shared__ float ssum[CLS_CAP];
    __shared__ float red[256];
    __shared__ float redc[256];
    int t = threadIdx.x;
    if (t < CLS_CAP) ssum[t] = 0.0f;
    int c = cls_cnt[cls];
    if (t < c) rs[t] = cls_rows[cls * CLS_CAP + t];
    __syncthreads();
    // reduce the 64 neg partials per row: 16 float4 loads each
    if (t < c) {
        int row = rs[t];
        const float4* ps4 = (const float4*)(part_sum + (size_t)row * NT);
        const float4* pm4 = (const float4*)(part_max + (size_t)row * NT);
        float s = 0.0f, m = -__builtin_inff();
#pragma unroll
        for (int k = 0; k < NT / 4; ++k) {
            float4 v = ps4[k];
            s += v.x + v.y + v.z + v.w;
            float4 u = pm4[k];
            m = fmaxf(m, fmaxf(fmaxf(u.x, u.y), fmaxf(u.z, u.w)));
        }
        sneg[t] = s;
        snm[t] = m;
    }
    __syncthreads();
    int np = c * (c - 1) / 2;
    if (np <= PCAP) {
        for (int p = t; p < np; p += 256) {
            float s = psims[cls * PCAP + p];
            int a, b; pair_decode(p, a, b);
            float e = __expf(-ALPHA * (s - BASE));
            if (s - MARGIN < snm[a]) atomicAdd(&ssum[a], e);
            if (s - MARGIN < snm[b]) atomicAdd(&ssum[b], e);
        }
    } else {
        // fallback: recompute dots, 8 lanes per pair
        for (int base = 0; base < np * 8; base += 256) {
            int slot = base + t;
            if (slot < np * 8) {
                int p = slot >> 3, l = slot & 7;
                int a, b; pair_decode(p, a, b);
                const float4* pa = (const float4*)(emb + (size_t)rs[a] * D_SIZE) + l * 8;
                const float4* pb = (const float4*)(emb + (size_t)rs[b] * D_SIZE) + l * 8;
                float s = 0.0f;
#pragma unroll
                for (int k = 0; k < 8; ++k) {
                    float4 x = pa[k], y = pb[k];
                    s = fmaf(x.x, y.x, fmaf(x.y, y.y, fmaf(x.z, y.z, fmaf(x.w, y.w, s))));
                }
                s += __shfl_xor(s, 1, 64);
                s += __shfl_xor(s, 2, 64);
                s += __shfl_xor(s, 4, 64);
                if (l == 0) {
                    float e = __expf(-ALPHA * (s - BASE));
                    if (s - MARGIN < snm[a]) atomicAdd(&ssum[a], e);
                    if (s - MARGIN < snm[b]) atomicAdd(&ssum[b], e);
                }
            }
        }
    }
    __syncthreads();
    float term = 0.0f, valid = 0.0f;
    if (t < c) {
        float sp = ssum[t], sn = sneg[t];
        if (sp > 0.0f && sn > 0.0f) {
            term = log1pf(sp) * (1.0f / ALPHA) + log1pf(sn) * (1.0f / BETA);
            valid = 1.0f;
        }
    }
    red[t] = term; redc[t] = valid;
    __syncthreads();
    for (int s = 128; s > 0; s >>= 1) {
        if (t < s) { red[t] += red[t + s]; redc[t] += redc[t + s]; }
        __syncthreads();
    }
    if (t == 0) {
        atomicAdd(gtot, red[0]);
        atomicAdd(gcnt, redc[0]);
        __threadfence();
        unsigned int tk = atomicAdd(gdone, 1u);
        if (tk == N_CLS - 1) {
            float T = __hip_atomic_load(gtot, __ATOMIC_RELAXED, __HIP_MEMORY_SCOPE_AGENT);
            float C = __hip_atomic_load(gcnt, __ATOMIC_RELAXED, __HIP_MEMORY_SCOPE_AGENT);
            out[0] = T / fmaxf(C, 1.0f);
        }
    }
}

extern "C" void kernel_launch(void* const* d_in, const int* in_sizes, int n_in,
                              void* d_out, int out_size, void* d_ws, size_t ws_size,
                              hipStream_t stream) {
    const float* emb = (const float*)d_in[0];
    const int* labels = (const int*)d_in[1];
    float* out = (float*)d_out;

    // ws layout: bf16 emb (4 MB) | pos_min (32 KB) | part_sum (2 MB) |
    //            part_max (2 MB) | psims (1 MB) | cls_rows (256 KB) |
    //            cls_cnt (4 KB) | gtot, gcnt, gdone
    unsigned short* embb = (unsigned short*)d_ws;
    float* pos_min = (float*)(embb + (size_t)B_SIZE * D_SIZE);
    float* part_sum = pos_min + B_SIZE;
    float* part_max = part_sum + (size_t)NT * B_SIZE;
    float* psims = part_max + (size_t)NT * B_SIZE;
    int* cls_rows = (int*)(psims + (size_t)N_CLS * PCAP);
    int* cls_cnt = cls_rows + N_CLS * CLS_CAP;
    float* gtot = (float*)(cls_cnt + N_CLS);
    float* gcnt = gtot + 1;
    unsigned int* gdone = (unsigned int*)(gcnt + 1);

    prep_kernel<<<dim3(B_SIZE * D_SIZE / 1024), dim3(256), 0, stream>>>(emb, embb, gtot, gcnt, gdone);
    pos_kernel<<<dim3(N_CLS), dim3(256), 0, stream>>>(emb, labels, pos_min, psims, cls_cnt, cls_rows);
    neg_kernel<<<dim3(NBLK), dim3(256), 0, stream>>>(embb, labels, pos_min, part_sum, part_max);
    posum_final_kernel<<<dim3(N_CLS), dim3(256), 0, stream>>>(emb, cls_cnt, cls_rows, psims,
                                                              part_sum, part_max,
                                                              gtot, gcnt, gdone, out);
}